// Round 10
// baseline (82.251 us; speedup 1.0000x reference)
//
#include <hip/hip_runtime.h>

typedef unsigned int uint;

#define NEG_SLOPE 0.2f
#define RSH  6
#define RBIN 64
#define MAXB 1024
#define SB   256       // sort blocks (== block size; thread j reads run j)

// Algebra: out = mean_n(GATConv) = (1/N) * (sum_e alpha_e * x[src_e]) @ W + bias,
// per-node logits a_s = x@(W@att_src), a_d = x@(W@att_dst). h=x@W never built;
// softmax max-subtraction dropped (logits ~N(0,4), exp<=~6e4, fp32 safe).
//
// gfx950 lessons:
//  - fp32 device atomics are memory-side RMWs regardless of scope (scattered
//    ~19/ns, same-address ~1/ns chip-wide) -> zero device atomics anywhere.
//  - grid.sync() cooperative phasing: catastrophic (round 7: 864us).
//  - single-block serial reduce: ~300cy exposed latency per iter (round 8:
//    120us) -> reductions must be multi-block AND pipelined.
//  - launch gap ~5-6us -> 5 launches: K1{prep|block-local sort} K2{node}
//    K3{denom} K4{alpha+colsum} K5{t-reduce+GEMV}.
//  - block-local sort: each sort-block scatters its own E/SB chunk compactly
//    into its own region + writes per-(block,bin) starts; consumers read bin b
//    as SB runs (thread j <-> run j, ~4 recs each, L2-resident). Eliminates
//    the global offs scan and the scattered global scatter pass.
//  - self-loops handled analytically inside K3/K4 (records = edges only).

// ---------------- K1: blk0 = prep (wsv,wdv); blks 1..SB = local sort ----------------
__global__ void k1_prep_sort(const float* __restrict__ W, const float* __restrict__ att_src,
                             const float* __restrict__ att_dst, const int* __restrict__ ei,
                             float* __restrict__ wsv, float* __restrict__ wdv,
                             uint* __restrict__ gStartA, uint* __restrict__ gStartB,
                             uint* __restrict__ recA, uint* __restrict__ recB,
                             int E, int B, int CH, int F_out) {
    __shared__ uint histA[MAXB], histB[MAXB];
    __shared__ uint startA[MAXB], startB[MAXB];
    __shared__ uint scan[SB];
    int tid = threadIdx.x, blk = blockIdx.x;

    if (blk == 0) {
        __shared__ float l_as[256], l_ad[256];
        if (tid < 200) { l_as[tid] = att_src[tid]; l_ad[tid] = att_dst[tid]; }
        __syncthreads();
        if (tid < 200) {
            int k = tid >> 1, j = tid & 1;
            const float* row = W + (size_t)k * F_out + j * 100;
            float s0 = 0.f, s1 = 0.f;
            #pragma unroll
            for (int i = 0; i < 100; ++i) {
                float w = row[i];
                s0 = fmaf(w, l_as[j * 100 + i], s0);
                s1 = fmaf(w, l_ad[j * 100 + i], s1);
            }
            s0 += __shfl_xor(s0, 1);
            s1 += __shfl_xor(s1, 1);
            if (j == 0) { wsv[k] = s0; wdv[k] = s1; }
        }
        return;
    }

    int sb = blk - 1;
    int i0 = sb * CH, i1 = min(E, i0 + CH);
    // pass 1: histogram both keys (one read of the chunk)
    for (int b = tid; b < B; b += SB) { histA[b] = 0u; histB[b] = 0u; }
    __syncthreads();
    for (int i = i0 + tid; i < i1; i += SB) {
        int s = ei[i], d = ei[E + i];
        atomicAdd(&histA[d >> RSH], 1u);
        atomicAdd(&histB[s >> RSH], 1u);
    }
    __syncthreads();
    // packed exclusive scan (A low16 | B high16; per-chunk counts <= CH < 65536)
    int b0 = tid * 4;
    uint hA[4], hB[4];
    uint sA = 0, sBv = 0;
    #pragma unroll
    for (int j = 0; j < 4; ++j) {
        int b = b0 + j;
        hA[j] = (b < B) ? histA[b] : 0u;
        hB[j] = (b < B) ? histB[b] : 0u;
        sA += hA[j]; sBv += hB[j];
    }
    uint packed = sA | (sBv << 16);
    scan[tid] = packed;
    __syncthreads();
    #pragma unroll
    for (int off = 1; off < SB; off <<= 1) {
        uint y = (tid >= off) ? scan[tid - off] : 0u;
        __syncthreads();
        scan[tid] += y;
        __syncthreads();
    }
    uint excl = scan[tid] - packed;
    uint rA = excl & 0xFFFFu, rB = excl >> 16;
    #pragma unroll
    for (int j = 0; j < 4; ++j) {
        int b = b0 + j;
        if (b < B) {
            startA[b] = rA; rA += hA[j];
            startB[b] = rB; rB += hB[j];
        }
    }
    __syncthreads();
    // write starts (+ sentinel) to global
    size_t gbase = (size_t)sb * (B + 1);
    for (int b = tid; b < B; b += SB) {
        gStartA[gbase + b] = startA[b];
        gStartB[gbase + b] = startB[b];
    }
    if (tid == 0) {
        gStartA[gbase + B] = (uint)(i1 - i0);
        gStartB[gbase + B] = (uint)(i1 - i0);
    }
    __syncthreads();
    // pass 2: scatter into own compact region (chunk re-read is L2-hot)
    uint rbase = (uint)sb * (uint)CH;
    for (int i = i0 + tid; i < i1; i += SB) {
        int s = ei[i], d = ei[E + i];
        uint pA = atomicAdd(&startA[d >> RSH], 1u);
        recA[rbase + pA] = ((uint)(d & (RBIN - 1)) << 16) | (uint)s;
        uint pB = atomicAdd(&startB[s >> RSH], 1u);
        recB[rbase + pB] = ((uint)(s & (RBIN - 1)) << 16) | (uint)d;
    }
}

// ---------------- K2: node logits (coalesced quads, 10 rows/block) ----------------
__global__ void k2_node(const float* __restrict__ x, const float* __restrict__ wsv,
                        const float* __restrict__ wdv, float* __restrict__ a_s,
                        float* __restrict__ a_d, int N) {
    __shared__ float lws[100], lwd[100];
    __shared__ float p0[256], p1[256];
    int tid = threadIdx.x, blk = blockIdx.x;
    if (tid < 100) { lws[tid] = wsv[tid]; lwd[tid] = wdv[tid]; }
    __syncthreads();
    int r = tid / 25, q = tid - r * 25;
    int row = blk * 10 + r;
    float s0 = 0.f, s1 = 0.f;
    if (tid < 250 && row < N) {
        float4 v = *reinterpret_cast<const float4*>(x + (size_t)row * 100 + q * 4);
        const float* ws = lws + q * 4;
        const float* wd = lwd + q * 4;
        s0 = v.x * ws[0] + v.y * ws[1] + v.z * ws[2] + v.w * ws[3];
        s1 = v.x * wd[0] + v.y * wd[1] + v.z * wd[2] + v.w * wd[3];
    }
    p0[tid] = s0;
    p1[tid] = s1;
    __syncthreads();
    if (tid < 20) {
        int rr = tid >> 1;
        int row2 = blk * 10 + rr;
        if (row2 < N) {
            const float* pp = (tid & 1) ? p1 : p0;
            float acc = 0.f;
            #pragma unroll
            for (int j = 0; j < 25; ++j) acc += pp[rr * 25 + j];
            if (tid & 1) a_d[row2] = acc;
            else         a_s[row2] = acc;
        }
    }
}

// ---------------- K3: denom per dst-bin (runs gather, self analytic) -> dd ----------------
__global__ void k3_denom(const uint* __restrict__ gStartA, const uint* __restrict__ recA,
                         const float* __restrict__ a_s, const float* __restrict__ a_d,
                         float2* __restrict__ dd, int N, int B, int CH) {
    __shared__ float lad[RBIN];
    __shared__ float acc[RBIN];
    int tid = threadIdx.x, b = blockIdx.x;
    if (tid < RBIN) {
        int node = b * RBIN + tid;
        float ad = 0.f, v = 0.f;
        if (node < N) {
            ad = a_d[node];
            float e = a_s[node] + ad;            // self loop
            e = (e >= 0.f) ? e : NEG_SLOPE * e;
            v = __expf(e);
        }
        lad[tid] = ad;
        acc[tid] = v;
    }
    __syncthreads();
    // thread j handles sort-block j's run for this bin
    size_t gb = (size_t)tid * (B + 1) + b;
    uint s0 = gStartA[gb], s1 = gStartA[gb + 1];
    uint rbase = (uint)tid * (uint)CH;
    for (uint p = s0; p < s1; ++p) {
        uint rec = recA[rbase + p];
        int src = rec & 0xFFFF;
        int dl = rec >> 16;
        float e = a_s[src] + lad[dl];
        e = (e >= 0.f) ? e : NEG_SLOPE * e;
        atomicAdd(&acc[dl], __expf(e));
    }
    __syncthreads();
    if (tid < RBIN) {
        int node = b * RBIN + tid;
        if (node < N) dd[node] = make_float2(lad[tid], acc[tid]);
    }
}

// ---------------- K4: alpha per src-bin (runs gather, self analytic) + colsum ----------------
__global__ void k4_alpha_colsum(const uint* __restrict__ gStartB, const uint* __restrict__ recB,
                                const float* __restrict__ a_s, const float2* __restrict__ dd,
                                const float* __restrict__ x, float* __restrict__ part,
                                int N, int B, int CH) {
    __shared__ float las[RBIN];
    __shared__ float acc[RBIN];
    __shared__ float4 red[256];
    int tid = threadIdx.x, b = blockIdx.x;
    if (tid < RBIN) {
        int node = b * RBIN + tid;
        float asv = 0.f, v = 0.f;
        if (node < N) {
            asv = a_s[node];
            float2 d2 = dd[node];                // self loop: dst == node
            float e = asv + d2.x;
            e = (e >= 0.f) ? e : NEG_SLOPE * e;
            v = __expf(e) / d2.y;
        }
        las[tid] = asv;
        acc[tid] = v;
    }
    __syncthreads();
    size_t gb = (size_t)tid * (B + 1) + b;
    uint s0 = gStartB[gb], s1 = gStartB[gb + 1];
    uint rbase = (uint)tid * (uint)CH;
    for (uint p = s0; p < s1; ++p) {
        uint rec = recB[rbase + p];
        int dst = rec & 0xFFFF;
        int sl = rec >> 16;
        float2 d2 = dd[dst];
        float e = las[sl] + d2.x;
        e = (e >= 0.f) ? e : NEG_SLOPE * e;
        atomicAdd(&acc[sl], __expf(e) / d2.y);
    }
    __syncthreads();
    // fused colsum: part[b][k] = sum_{l<64} acc[l] * x[b*64+l][k]
    int rg = tid >> 5;           // 8 row-groups
    int q  = tid & 31;           // quads 0..24 active
    float4 a = make_float4(0.f, 0.f, 0.f, 0.f);
    if (q < 25) {
        for (int rr = rg; rr < RBIN; rr += 8) {
            int row = b * RBIN + rr;
            if (row < N) {
                float w = acc[rr];
                float4 v = *reinterpret_cast<const float4*>(x + (size_t)row * 100 + q * 4);
                a.x = fmaf(w, v.x, a.x);
                a.y = fmaf(w, v.y, a.y);
                a.z = fmaf(w, v.z, a.z);
                a.w = fmaf(w, v.w, a.w);
            }
        }
    }
    red[tid] = a;
    __syncthreads();
    if (tid < 25) {
        float4 s = red[tid];
        #pragma unroll
        for (int g = 1; g < 8; ++g) {
            float4 bb = red[g * 32 + tid];
            s.x += bb.x; s.y += bb.y; s.z += bb.z; s.w += bb.w;
        }
        *reinterpret_cast<float4*>(part + (size_t)b * 128 + tid * 4) = s;
    }
}

// ---------------- K5: fused t-reduce + GEMV. 100 blocks; block j streams all of
// part (L2-resident) into lt[100], then computes out[2j], out[2j+1]. ----------------
__global__ void k5_final(const float* __restrict__ part, const float* __restrict__ W,
                         const float* __restrict__ bias, float* __restrict__ out,
                         int N, int B) {
    __shared__ float4 red[256];
    __shared__ float lt[128];
    __shared__ float rf[2][128];
    int tid = threadIdx.x, blk = blockIdx.x;
    // stream part: thread = quad q of row-group g (10 groups x 25 quads)
    int g = tid / 25, q = tid - g * 25;
    float4 a = make_float4(0.f, 0.f, 0.f, 0.f);
    if (tid < 250) {
        const float4* p4 = reinterpret_cast<const float4*>(part);
        for (int b = g; b < B; b += 10) {
            float4 v = p4[(size_t)b * 32 + q];
            a.x += v.x; a.y += v.y; a.z += v.z; a.w += v.w;
        }
    }
    red[tid] = a;
    __syncthreads();
    if (tid < 25) {
        float4 s = red[tid];
        #pragma unroll
        for (int gg = 1; gg < 10; ++gg) {
            float4 bb = red[gg * 25 + tid];
            s.x += bb.x; s.y += bb.y; s.z += bb.z; s.w += bb.w;
        }
        *reinterpret_cast<float4*>(lt + tid * 4) = s;
    }
    __syncthreads();
    // GEMV for f0 = 2*blk, f1 = 2*blk+1 (parallel dot + LDS tree)
    int f0 = 2 * blk, f1 = f0 + 1;
    float v0 = 0.f, v1 = 0.f;
    if (tid < 100) {
        float t = lt[tid];
        v0 = t * W[(size_t)tid * 200 + f0];
        v1 = t * W[(size_t)tid * 200 + f1];
    }
    rf[0][tid < 128 ? tid : 127] = 0.f;   // ensure init (tid>=128 writes dup, harmless)
    rf[1][tid < 128 ? tid : 127] = 0.f;
    __syncthreads();
    if (tid < 128) { rf[0][tid] = (tid < 100) ? v0 : 0.f; rf[1][tid] = (tid < 100) ? v1 : 0.f; }
    __syncthreads();
    for (int off = 64; off > 0; off >>= 1) {
        if (tid < off) {
            rf[0][tid] += rf[0][tid + off];
            rf[1][tid] += rf[1][tid + off];
        }
        __syncthreads();
    }
    if (tid == 0) {
        float inv = 1.f / (float)N;
        out[f0] = rf[0][0] * inv + bias[f0];
        out[f1] = rf[1][0] * inv + bias[f1];
    }
}

// ================= generic device-atomic tier (correctness-only fallback) =================

__global__ void fb_prep(const float* W, const float* att_src, const float* att_dst,
                        float* wsv, float* wdv, int F_in, int F_out) {
    for (int k = threadIdx.x; k < F_in; k += blockDim.x) {
        float s0 = 0.f, s1 = 0.f;
        for (int f = 0; f < F_out; ++f) {
            float w = W[(size_t)k * F_out + f];
            s0 = fmaf(w, att_src[f], s0);
            s1 = fmaf(w, att_dst[f], s1);
        }
        wsv[k] = s0; wdv[k] = s1;
    }
}
__global__ void fb_node(const float* x, const float* wsv, const float* wdv,
                        float* a_s, float* a_d, float* denom, float* s_src,
                        int N, int F_in) {
    int n = blockIdx.x * blockDim.x + threadIdx.x;
    if (n >= N) return;
    float s0 = 0.f, s1 = 0.f;
    for (int k = 0; k < F_in; ++k) {
        float v = x[(size_t)n * F_in + k];
        s0 = fmaf(v, wsv[k], s0);
        s1 = fmaf(v, wdv[k], s1);
    }
    a_s[n] = s0; a_d[n] = s1; denom[n] = 0.f; s_src[n] = 0.f;
}
__global__ void fb_denom(const int* ei, const float* a_s, const float* a_d,
                         float* denom, int E, int N) {
    int i = blockIdx.x * blockDim.x + threadIdx.x;
    if (i >= E + N) return;
    int src, dst;
    if (i < E) { src = ei[i]; dst = ei[E + i]; } else { src = dst = i - E; }
    float e = a_s[src] + a_d[dst];
    e = (e >= 0.f) ? e : NEG_SLOPE * e;
    atomicAdd(denom + dst, __expf(e));
}
__global__ void fb_alpha(const int* ei, const float* a_s, const float* a_d,
                         const float* denom, float* s_src, int E, int N) {
    int i = blockIdx.x * blockDim.x + threadIdx.x;
    if (i >= E + N) return;
    int src, dst;
    if (i < E) { src = ei[i]; dst = ei[E + i]; } else { src = dst = i - E; }
    float e = a_s[src] + a_d[dst];
    e = (e >= 0.f) ? e : NEG_SLOPE * e;
    atomicAdd(s_src + src, __expf(e) / denom[dst]);
}
__global__ void fb_colsum(const float* x, const float* s_src, float* t, int N, int F_in) {
    __shared__ float red[256];
    int k = blockIdx.x;
    float s = 0.f;
    for (int n = threadIdx.x; n < N; n += 256) s = fmaf(s_src[n], x[(size_t)n * F_in + k], s);
    red[threadIdx.x] = s;
    __syncthreads();
    for (int off = 128; off > 0; off >>= 1) {
        if (threadIdx.x < off) red[threadIdx.x] += red[threadIdx.x + off];
        __syncthreads();
    }
    if (threadIdx.x == 0) t[k] = red[0];
}
__global__ void fb_final(const float* t, const float* W, const float* bias, float* out,
                         int N, int F_in, int F_out) {
    int f = blockIdx.x * blockDim.x + threadIdx.x;
    if (f >= F_out) return;
    float acc = 0.f;
    for (int k = 0; k < F_in; ++k) acc = fmaf(t[k], W[(size_t)k * F_out + f], acc);
    out[f] = acc / (float)N + bias[f];
}

extern "C" void kernel_launch(void* const* d_in, const int* in_sizes, int n_in,
                              void* d_out, int out_size, void* d_ws, size_t ws_size,
                              hipStream_t stream) {
    const float* x       = (const float*)d_in[0];
    const int*   ei      = (const int*)d_in[1];
    const float* W       = (const float*)d_in[2];
    const float* att_src = (const float*)d_in[3];
    const float* att_dst = (const float*)d_in[4];
    const float* bias    = (const float*)d_in[5];
    float* out = (float*)d_out;

    const int F_out = in_sizes[3];             // 200
    const int F_in  = in_sizes[2] / F_out;     // 100
    const int N     = in_sizes[0] / F_in;      // 50000
    const int E     = in_sizes[1] / 2;         // 800000
    const int B     = (N + RBIN - 1) >> RSH;   // 782
    const int CH    = (E + SB - 1) / SB;       // 3125 edges per sort block
    const int NODEB = (N + 9) / 10;            // 5000

    // ---- workspace layout (floats) ----
    float* ws = (float*)d_ws;
    size_t off = 0;
    float* wsv   = ws + off; off += 128;
    float* wdv   = ws + off; off += 128;
    float* t     = ws + off; off += 128;        // fallback tier only
    float* a_s   = ws + off; off += N;
    float* a_d   = ws + off; off += N;
    float* denom = ws + off; off += N;          // fallback tier only
    float* s_src = ws + off; off += N;          // fallback tier only
    off = (off + 1) & ~(size_t)1;               // 8B align for float2
    float2* dd   = (float2*)(ws + off); off += 2 * (size_t)N;
    uint* gStartA = (uint*)(ws + off); off += (size_t)SB * (B + 1);
    uint* gStartB = (uint*)(ws + off); off += (size_t)SB * (B + 1);
    uint* recA    = (uint*)(ws + off); off += (size_t)SB * CH;
    uint* recB    = (uint*)(ws + off); off += (size_t)SB * CH;
    float* part   = ws + off; off += (size_t)B * 128;
    size_t need_bytes = off * 4;

    bool sort_ok = (ws_size >= need_bytes) && (B <= MAXB) && (N <= 65535) &&
                   (CH <= 65535) && (F_in == 100) && (F_out == 200);

    if (sort_ok) {
        k1_prep_sort<<<1 + SB, SB, 0, stream>>>(W, att_src, att_dst, ei, wsv, wdv,
                                                gStartA, gStartB, recA, recB,
                                                E, B, CH, F_out);
        k2_node<<<NODEB, 256, 0, stream>>>(x, wsv, wdv, a_s, a_d, N);
        k3_denom<<<B, SB, 0, stream>>>(gStartA, recA, a_s, a_d, dd, N, B, CH);
        k4_alpha_colsum<<<B, SB, 0, stream>>>(gStartB, recB, a_s, dd, x, part, N, B, CH);
        k5_final<<<100, 256, 0, stream>>>(part, W, bias, out, N, B);
    } else {
        fb_prep<<<1, 256, 0, stream>>>(W, att_src, att_dst, wsv, wdv, F_in, F_out);
        fb_node<<<(N + 255) / 256, 256, 0, stream>>>(x, wsv, wdv, a_s, a_d, denom, s_src, N, F_in);
        int grid = (E + N + 255) / 256;
        fb_denom<<<grid, 256, 0, stream>>>(ei, a_s, a_d, denom, E, N);
        fb_alpha<<<grid, 256, 0, stream>>>(ei, a_s, a_d, denom, s_src, E, N);
        fb_colsum<<<F_in, 256, 0, stream>>>(x, s_src, t, N, F_in);
        fb_final<<<(F_out + 255) / 256, 256, 0, stream>>>(t, W, bias, out, N, F_in, F_out);
    }
}